// Round 9
// baseline (414.788 us; speedup 1.0000x reference)
//
#include <hip/hip_runtime.h>
#include <hip/hip_bf16.h>

#define HW 4096

// ---------------- d_out layout ----------------
// bf16 elements:
//   [0         .. 1,048,576)  q_t [4][4096 n][64 c]   (c: 0..31 br1-q, 32..63 br2-q)
//   [1,048,576 .. 3,145,728)  k_t [2][4][4096 m][64 c]
// fp32 elements:
//   [1,572,864 .. 1,753,088)  wtp [2][256][352] transposed proj weights
//   [4,194,304 .. 8,388,608)  out1 (final, written by attn phase-2)
//   [8,388,608 .. 12,582,912) out2
// Scratch region [0..4,194,304 floats) is overwritten by conv output at the end.
// d_ws: wt_conv bf16 [32][9][256][16] = 2,359,296 B @ 0
//       wv_bf  bf16 [2][256 o][256 c] =   262,144 B @ 2,359,296
#define KT_OFF   1048576        // bf16 elements
#define WTP_OFF  1572864        // float elements
#define O1_OFF   4194304        // float elements
#define WVB_OFF  1179648        // bf16 elements into d_ws

typedef short v8s  __attribute__((ext_vector_type(8)));
typedef float v16f __attribute__((ext_vector_type(16)));

#define LSTR 72                 // attention LDS row stride (bf16)
#define ZSTR 264                // zt row stride (shorts): 528 B, 16B-aligned, bank-stride 33 (cf-free)
#define PL_ROWS 128             // plds rows (BN)
#define PL_SZ  (2 * PL_ROWS * LSTR)   // shorts, both plds buffers
#define XP_SZ  (2 * 256 * LSTR)       // shorts, both xpriv buffers
#define CPAD2 24                // conv v4 ci-stride (shorts): 48 B -> 16B-aligned b128 reads
#define XSLOT 198               // conv v4 pixel slots: 3 rows x 66 cols
#define XLH2  (XSLOT * CPAD2)   // shorts per conv x buffer (4752)

__device__ __forceinline__ unsigned short f2b(float f) {   // fp32 -> bf16 RNE (host-side preps)
    unsigned u = __float_as_uint(f);
    return (unsigned short)((u + 0x7fffu + ((u >> 16) & 1u)) >> 16);
}
__device__ __forceinline__ unsigned cvt_pk_bf16(float lo, float hi) {  // HW RNE pack via intrinsic
    float2 f2; f2.x = lo; f2.y = hi;
    __hip_bfloat162 h = __float22bfloat162_rn(f2);
    unsigned r;
    __builtin_memcpy(&r, &h, 4);
    return r;
}
__device__ __forceinline__ v8s load8(const unsigned short* p) {  // 8 bf16 via two b64 (8B-aligned)
    union { uint2 u[2]; v8s v; } t;
    t.u[0] = *(const uint2*)p;
    t.u[1] = *(const uint2*)(p + 4);
    return t.v;
}

// ---------------- weight prep: proj weights -> [sel][c][co(352)] fp32 ----------------
__global__ __launch_bounds__(256) void wprep_proj(
    const float* __restrict__ wq1, const float* __restrict__ wk1, const float* __restrict__ wv1,
    const float* __restrict__ wq2, const float* __restrict__ wk2, const float* __restrict__ wv2,
    float* __restrict__ wtp) {
    int idx = blockIdx.x * 256 + threadIdx.x;        // 2*256*352 = 180,224 total
    if (idx >= 2 * 256 * 352) return;
    int sel = idx / 90112;
    int r   = idx - sel * 90112;
    int c   = r / 352;
    int co  = r - c * 352;
    const float* w; int row;
    if (co < 32)      { w = sel ? wq2 : wq1; row = co; }
    else if (co < 96) { w = sel ? wk2 : wk1; row = co - 32; }
    else              { w = sel ? wv2 : wv1; row = co - 96; }
    wtp[idx] = w[row * 256 + c];
}

// ---------------- weight prep: conv w -> bf16 [chunk][tap][o][ci16] ----------------
__global__ __launch_bounds__(256) void wprep_convw(const float* __restrict__ wcat,
                                                   unsigned short* __restrict__ wt) {
    int i = blockIdx.x * 256 + threadIdx.x;          // 1,179,648 total
    if (i >= 32 * 9 * 256 * 16) return;
    const int ci_l = i & 15;
    const int o    = (i >> 4) & 255;
    const int t2   = i >> 12;
    const int tap  = t2 % 9;
    const int chunk = t2 / 9;
    wt[i] = f2b(wcat[((size_t)o * 512 + chunk * 16 + ci_l) * 9 + tap]);
}

// ---------------- weight prep: wv -> bf16 [2][o][c] ----------------
__global__ __launch_bounds__(256) void wprep_wv(const float* __restrict__ wv1,
                                                const float* __restrict__ wv2,
                                                unsigned short* __restrict__ out) {
    int i = blockIdx.x * 256 + threadIdx.x;          // 131,072 total
    if (i >= 131072) return;
    const float* src = (i < 65536) ? wv1 : wv2;
    out[i] = f2b(src[i & 65535]);
}

// ---------------- projections: q|k = W x + b -> bf16 transposed q_t/k_t ----------------
__global__ __launch_bounds__(256) void proj_kernel(
    const float* __restrict__ x1, const float* __restrict__ x2,
    const float* __restrict__ bq1, const float* __restrict__ bk1,
    const float* __restrict__ bq2, const float* __restrict__ bk2,
    float* __restrict__ dout) {
    __shared__ __align__(16) float xls[256][64];     // 64 KB
    const int tile = blockIdx.x, sel = blockIdx.y, b = blockIdx.z;
    const int n0 = tile * 64;
    const float* xb = (sel ? x2 : x1) + (size_t)b * 256 * HW;

    for (int i = threadIdx.x; i < 4096; i += 256) {
        const int row = i >> 4, c4 = (i & 15) * 4;
        *(float4*)&xls[row][c4] = *(const float4*)(xb + (size_t)row * HW + n0 + c4);
    }
    __syncthreads();

    const int n   = threadIdx.x & 63;
    const int cog = __builtin_amdgcn_readfirstlane(threadIdx.x >> 6);   // 0..3, wave-uniform
    const float* bq = sel ? bq2 : bq1;
    const float* bk = sel ? bk2 : bk1;
    const float* wc = dout + WTP_OFF + (size_t)sel * 90112;   // [c][352]
    unsigned short* qtg = (unsigned short*)dout + (size_t)b * HW * 64;
    unsigned short* ktg = (unsigned short*)dout + KT_OFF + (size_t)(sel * 4 + b) * HW * 64;

    for (int blk = 0; blk < 3; ++blk) {              // 4 groups * 24 co = 96
        const int co0 = cog * 24 + blk * 8;          // never straddles the q/k split at 32
        float acc[8];
        const float* brow; int r0; bool isq;
        if (co0 < 32) { r0 = co0;      brow = bq; isq = true;  }
        else          { r0 = co0 - 32; brow = bk; isq = false; }
        #pragma unroll
        for (int k = 0; k < 8; ++k) acc[k] = brow[r0 + k];
        #pragma unroll 4
        for (int c = 0; c < 256; ++c) {
            const float xv = xls[c][n];
            const float4 w0 = *(const float4*)(wc + (size_t)c * 352 + co0);
            const float4 w1 = *(const float4*)(wc + (size_t)c * 352 + co0 + 4);
            acc[0] += xv * w0.x; acc[1] += xv * w0.y; acc[2] += xv * w0.z; acc[3] += xv * w0.w;
            acc[4] += xv * w1.x; acc[5] += xv * w1.y; acc[6] += xv * w1.z; acc[7] += xv * w1.w;
        }
        unsigned pk2[4];
        #pragma unroll
        for (int k = 0; k < 4; ++k) pk2[k] = cvt_pk_bf16(acc[2 * k], acc[2 * k + 1]);
        unsigned short* dst = isq ? (qtg + (size_t)(n0 + n) * 64 + sel * 32 + r0)
                                  : (ktg + (size_t)(n0 + n) * 64 + r0);
        *(uint4*)dst = *(const uint4*)pk2;           // 16B store
    }
}

// ---------------- MFMA attention + fused mix ----------------
// BN=128 per block, 8 waves, 256 blocks = 1 block/CU, XCD swizzle: g=bid&7 <-> (br,b).
__global__ __launch_bounds__(512, 2) void attn_kernel(
    const float* __restrict__ in1, const float* __restrict__ in2,
    const unsigned short* __restrict__ wvbf,         // [2][256 o][256 c] bf16
    const float* __restrict__ bv1, const float* __restrict__ bv2,
    const float* __restrict__ gamma_p,
    float* __restrict__ dout) {
    __shared__ __align__(16) unsigned short smem[PL_SZ + XP_SZ];   // 110,592 B
    __shared__ float rsums[128][2];
    __shared__ float lfin[128];

    const int bid = blockIdx.x;          // 0..255
    const int g   = bid & 7;             // XCD group == (br,b)
    const int qt  = bid >> 3;            // 0..31
    const int br  = g >> 2, b = g & 3;
    const int t = threadIdx.x;
    const int w = t >> 6, lane = t & 63, h = lane >> 5, l32 = lane & 31;

    const unsigned short* qtg = (const unsigned short*)dout + (size_t)b * HW * 64;
    const unsigned short* ktg = (const unsigned short*)dout + KT_OFF + (size_t)(br * 4 + b) * HW * 64;
    const float* xg = (br ? in2 : in1) + (size_t)b * 256 * HW;
    float* zo = dout + O1_OFF + (size_t)br * 4194304 + (size_t)b * 256 * HW;

    // wave roles
    const int msub = (w & 1) * 32;       // S^T m-subtile
    const int nsub = (w >> 1) * 32;      // S^T n-subtile (0..96)
    const int cs   = w & 3;              // zacc c-slice / phase-2 o-slice
    const int nh   = w >> 2;             // zacc / phase-2 n-half (0..1)
    const int koff = h * 8;

    unsigned short* plds = smem;                 // [2][128][LSTR]
    unsigned short* xp   = smem + PL_SZ;         // [2][256][LSTR]

    // persistent Q fragments (S^T B-operand): rows qt*128 + nsub + l32
    v8s aq[4];
    #pragma unroll
    for (int ks = 0; ks < 4; ++ks)
        aq[ks] = *(const v8s*)(qtg + (size_t)(qt * 128 + nsub + l32) * 64 + ks * 16 + koff);

    // K fragment lane base (S^T A-operand): rows mt*64 + msub + l32
    const unsigned short* kpt = ktg + (size_t)(msub + l32) * 64 + koff;
    v8s kf[4];
    #pragma unroll
    for (int ks = 0; ks < 4; ++ks)
        kf[ks] = *(const v8s*)(kpt + ks * 16);

    // x staging: 512 threads stage X[256 c][64 m] per iter.
    const int m4 = (t & 15) * 4, r0i = t >> 4;     // r0i 0..31
    const float* xgp = xg + (size_t)r0i * HW + m4;

    uint2 xpk[8];                // packed bf16 x-tile (pending LDS store)
    {
        float4 xr0[8];
        #pragma unroll
        for (int j = 0; j < 8; ++j) xr0[j] = *(const float4*)(xgp + (size_t)j * 32 * HW);
        #pragma unroll
        for (int j = 0; j < 8; ++j) {
            xpk[j].x = cvt_pk_bf16(xr0[j].x, xr0[j].y);
            xpk[j].y = cvt_pk_bf16(xr0[j].z, xr0[j].w);
        }
    }

    v16f a00, a01, a10, a11;
    #pragma unroll
    for (int i = 0; i < 16; ++i) { a00[i] = 0.f; a01[i] = 0.f; a10[i] = 0.f; a11[i] = 0.f; }
    float racc = 0.f;

    #pragma unroll 1
    for (int mt = 0; mt < 64; ++mt) {
        const int cur = mt & 1;
        // ---- S^T = K Q^T, pure-register MFMA ----
        v16f s;
        #pragma unroll
        for (int i = 0; i < 16; ++i) s[i] = 0.f;
        #pragma unroll
        for (int ks = 0; ks < 4; ++ks)
            s = __builtin_amdgcn_mfma_f32_32x32x16_bf16(kf[ks], aq[ks], s, 0, 0, 0);
        const int mg = (mt < 63) ? (mt + 1) * 64 : 0;          // next tile (wraps harmlessly)
        // prefetch next K fragments
        #pragma unroll
        for (int ks = 0; ks < 4; ++ks)
            kf[ks] = *(const v8s*)(kpt + (size_t)mg * 64 + ks * 16);
        // issue ALL next-tile x loads (full-iteration latency cover)
        float4 xr[8];
        #pragma unroll
        for (int j = 0; j < 8; ++j)
            xr[j] = *(const float4*)(xgp + (size_t)j * 32 * HW + mg);
        // ---- P = exp(S^T): scalar row sum, packed m-pairs ----
        unsigned short* prow = plds + (size_t)(cur * PL_ROWS + nsub + l32) * LSTR + msub;
        #pragma unroll
        for (int rp = 0; rp < 8; ++rp) {
            const float e0 = __expf(s[2 * rp]);
            const float e1 = __expf(s[2 * rp + 1]);
            racc += e0 + e1;
            const int m0 = ((2 * rp) & 3) + 8 * (rp >> 1) + 4 * h;   // even
            *(unsigned*)&prow[m0] = cvt_pk_bf16(e0, e1);
        }
        // ---- write current X tile (converted last iter) ----
        {
            unsigned short* xw = xp + (size_t)(cur * 256 + r0i) * LSTR + m4;
            #pragma unroll
            for (int j = 0; j < 8; ++j)
                *(uint2*)(xw + (size_t)j * 32 * LSTR) = xpk[j];
        }
        __syncthreads();         // ONE barrier: P/X visible; prior-buffer reads drained
        // ---- zacc: a[c-slice][n-half] += X P^T ----
        {
            const unsigned short* xb0 = xp + (size_t)(cur * 256 + cs * 64 + l32) * LSTR;
            const unsigned short* xb1 = xb0 + (size_t)32 * LSTR;
            const unsigned short* pb0 = plds + (size_t)(cur * PL_ROWS + nh * 64 + l32) * LSTR;
            const unsigned short* pb1 = pb0 + (size_t)32 * LSTR;
            #pragma unroll
            for (int ks = 0; ks < 4; ++ks) {
                const int mo = ks * 16 + koff;
                const v8s xa0 = *(const v8s*)(xb0 + mo);
                const v8s xa1 = *(const v8s*)(xb1 + mo);
                const v8s pf0 = *(const v8s*)(pb0 + mo);
                const v8s pf1 = *(const v8s*)(pb1 + mo);
                a00 = __builtin_amdgcn_mfma_f32_32x32x16_bf16(xa0, pf0, a00, 0, 0, 0);
                a01 = __builtin_amdgcn_mfma_f32_32x32x16_bf16(xa0, pf1, a01, 0, 0, 0);
                a10 = __builtin_amdgcn_mfma_f32_32x32x16_bf16(xa1, pf0, a10, 0, 0, 0);
                a11 = __builtin_amdgcn_mfma_f32_32x32x16_bf16(xa1, pf1, a11, 0, 0, 0);
            }
        }
        // convert next x tile (loads had the whole iteration to land)
        #pragma unroll
        for (int j = 0; j < 8; ++j) {
            xpk[j].x = cvt_pk_bf16(xr[j].x, xr[j].y);
            xpk[j].y = cvt_pk_bf16(xr[j].z, xr[j].w);
        }
    }
    // ---- softmax denominators ----
    __syncthreads();
    {
        const float rtot = racc + __shfl_xor(racc, 32);
        if (lane < 32) rsums[nsub + l32][w & 1] = rtot;
    }
    __syncthreads();
    if (t < 128) lfin[t] = 1.0f / (rsums[t][0] + rsums[t][1]);
    __syncthreads();
    const float dn0 = lfin[nh * 64 + l32];
    const float dn1 = lfin[nh * 64 + 32 + l32];
    // ---- normalized z -> zt[n][c] bf16 (overlays smem; cf-free stride) ----
    unsigned short (*zt)[ZSTR] = (unsigned short (*)[ZSTR])smem;   // 128 x 264 shorts
    #pragma unroll
    for (int rp = 0; rp < 8; ++rp) {
        const int r = rp * 2;
        const int c = cs * 64 + (r & 3) + 8 * (r >> 2) + 4 * h;    // even; c(r+1)=c+1
        const int n0r = nh * 64 + l32, n1r = nh * 64 + 32 + l32;
        *(unsigned*)&zt[n0r][c]      = cvt_pk_bf16(a00[r] * dn0, a00[r + 1] * dn0);
        *(unsigned*)&zt[n1r][c]      = cvt_pk_bf16(a01[r] * dn1, a01[r + 1] * dn1);
        *(unsigned*)&zt[n0r][c + 32] = cvt_pk_bf16(a10[r] * dn0, a10[r + 1] * dn0);
        *(unsigned*)&zt[n1r][c + 32] = cvt_pk_bf16(a11[r] * dn1, a11[r + 1] * dn1);
    }
    __syncthreads();
    // ---- phase 2: out[o][n] = gamma * (Wv z + bv) + x ----
    const unsigned short* wvb = wvbf + (size_t)br * 65536;   // [o][c] bf16
    const float* bvp = br ? bv2 : bv1;
    const float gamma = gamma_p[0];
    const int ob = cs * 64;
    const int ncol = qt * 128 + nh * 64;
    v16f m00, m01, m10, m11;
    #pragma unroll
    for (int i = 0; i < 16; ++i) { m00[i] = 0.f; m01[i] = 0.f; m10[i] = 0.f; m11[i] = 0.f; }
    #pragma unroll
    for (int ks = 0; ks < 16; ++ks) {
        const int k = ks * 16 + koff;
        const v8s aA = *(const v8s*)(wvb + (size_t)(ob + l32) * 256 + k);
        const v8s aB = *(const v8s*)(wvb + (size_t)(ob + 32 + l32) * 256 + k);
        const v8s b0v = *(const v8s*)&zt[nh * 64 + l32][k];
        const v8s b1v = *(const v8s*)&zt[nh * 64 + 32 + l32][k];
        m00 = __builtin_amdgcn_mfma_f32_32x32x16_bf16(aA, b0v, m00, 0, 0, 0);
        m01 = __builtin_amdgcn_mfma_f32_32x32x16_bf16(aA, b1v, m01, 0, 0, 0);
        m10 = __builtin_amdgcn_mfma_f32_32x32x16_bf16(aB, b0v, m10, 0, 0, 0);
        m11 = __builtin_amdgcn_mfma_f32_32x32x16_bf16(aB, b1v, m11, 0, 0, 0);
    }
    #pragma unroll
    for (int r = 0; r < 16; ++r) {
        const int o = ob + (r & 3) + 8 * (r >> 2) + 4 * h;
        const float bvA = bvp[o], bvB = bvp[o + 32];
        const size_t base0 = (size_t)o * HW + ncol;
        const size_t base1 = (size_t)(o + 32) * HW + ncol;
        zo[base0 + l32]      = gamma * (m00[r] + bvA) + xg[base0 + l32];
        zo[base0 + 32 + l32] = gamma * (m01[r] + bvA) + xg[base0 + 32 + l32];
        zo[base1 + l32]      = gamma * (m10[r] + bvB) + xg[base1 + l32];
        zo[base1 + 32 + l32] = gamma * (m11[r] + bvB) + xg[base1 + 32 + l32];
    }
}

// ---------------- MFMA 3x3 conv (512->256) + BN + ReLU ----------------
// v4: 1-row tiles (grid 1024 -> 4 blocks/CU, 4 waves/SIMD), weights direct
// global->reg fragments (no wl LDS), 16B-aligned b128 x-reads, one barrier/chunk.
__global__ __launch_bounds__(256, 4) void conv_kernel(
    const unsigned short* __restrict__ wt,
    const float* __restrict__ bn_scale, const float* __restrict__ bn_bias,
    const float* __restrict__ bn_mean,  const float* __restrict__ bn_var,
    float* __restrict__ dout) {
    __shared__ __align__(16) unsigned short xl[2][XLH2];   // 19,008 B

    const int bid = blockIdx.x;                      // 0..1023
    const int lin = (bid & 7) * 128 + (bid >> 3);    // XCD-localized linear id (bijective)
    const int ot  = lin & 3;
    const int rowb = lin >> 2;                       // 0..255
    const int h0  = rowb & 63;                       // output row
    const int b   = rowb >> 6;
    const int t   = threadIdx.x;
    const int w   = t >> 6, lane = t & 63, h = lane >> 5, l32 = lane & 31;
    const int osub = (w & 1) * 32;
    const int px0  = (w >> 1) * 32;

    // staging descriptors: 1584 b32 units = 198 pixel slots x 8 ci-pairs
    int ldsoff[7], srcoff[7]; bool act[7], inb[7];
    #pragma unroll
    for (int k = 0; k < 7; ++k) {
        const int u = t + k * 256;
        act[k] = u < 1584;
        const int pix = u % 198, grp = u / 198;      // grp 0..7 (ci-pair)
        const int row = pix / 66, col = pix % 66;    // row 0..2, col 0..65
        const int hh = h0 + row - 1, ww = col - 1;
        inb[k] = act[k] && (hh >= 0 && hh < 64 && ww >= 0 && ww < 64);
        srcoff[k] = 2 * grp * HW + (inb[k] ? hh * 64 + ww : 0);
        ldsoff[k] = pix * CPAD2 + 2 * grp;
    }

    v16f acc;
    #pragma unroll
    for (int i = 0; i < 16; ++i) acc[i] = 0.f;

    const float* bsrc = dout + O1_OFF + (size_t)b * 1048576;
    const unsigned short* wbase = wt + (size_t)(ot * 64 + osub + l32) * 16 + h * 8;

    // prologue: x chunk 0 -> regs
    float xv0[7], xv1[7];
    #pragma unroll
    for (int k = 0; k < 7; ++k) {
        xv0[k] = 0.f; xv1[k] = 0.f;
        if (inb[k]) {
            const float* p = bsrc + srcoff[k];
            xv0[k] = p[0]; xv1[k] = p[HW];
        }
    }

    #pragma unroll 1
    for (int chunk = 0; chunk < 32; ++chunk) {
        const int cur = chunk & 1;
        // weight A-fragments for THIS chunk, direct from global (L2-resident, coalesced)
        v8s wf[9];
        {
            const unsigned short* wc = wbase + (size_t)chunk * 36864;
            #pragma unroll
            for (int tap = 0; tap < 9; ++tap)
                wf[tap] = *(const v8s*)(wc + (size_t)tap * 4096);
        }
        // write staged x regs -> LDS[cur]
        #pragma unroll
        for (int k = 0; k < 7; ++k)
            if (act[k])
                *(unsigned*)&xl[cur][ldsoff[k]] = cvt_pk_bf16(xv0[k], xv1[k]);
        // prefetch x for chunk+1
        if (chunk < 31) {
            const int cn = chunk + 1;
            const float* src = bsrc + (size_t)(cn < 16 ? 0 : 1) * 4194304
                             + (size_t)((cn & 15) * 16) * HW;
            #pragma unroll
            for (int k = 0; k < 7; ++k) {
                xv0[k] = 0.f; xv1[k] = 0.f;
                if (inb[k]) {
                    const float* p = src + srcoff[k];
                    xv0[k] = p[0]; xv1[k] = p[HW];
                }
            }
        }
        __syncthreads();         // LDS[cur] visible; chunk-2 reads of LDS[cur] drained
        // MFMA on LDS[cur]: 9 taps, B-frag = pixel (px0+l32+dx), row dy, ci h*8..+8
        #pragma unroll
        for (int dy = 0; dy < 3; ++dy) {
            #pragma unroll
            for (int dx = 0; dx < 3; ++dx) {
                const v8s bf = *(const v8s*)&xl[cur][(dy * 66 + px0 + l32 + dx) * CPAD2 + h * 8];
                acc = __builtin_amdgcn_mfma_f32_32x32x16_bf16(wf[dy * 3 + dx], bf, acc, 0, 0, 0);
            }
        }
    }
    // epilogue: BN params loaded here (not held across the loop -> low VGPR)
    const int px = px0 + l32;
    const size_t gp = (size_t)h0 * 64 + px;
    #pragma unroll
    for (int r = 0; r < 16; ++r) {
        const int o_g = ot * 64 + osub + (r & 3) + 8 * (r >> 2) + 4 * h;
        const float iv = bn_scale[o_g] * __frsqrt_rn(bn_var[o_g] + 1e-5f);
        const float ad = bn_bias[o_g] - bn_mean[o_g] * iv;
        float v = acc[r] * iv + ad;
        v = v > 0.f ? v : 0.f;
        dout[((size_t)b * 256 + o_g) * HW + gp] = v;
    }
}

extern "C" void kernel_launch(void* const* d_in, const int* in_sizes, int n_in,
                              void* d_out, int out_size, void* d_ws, size_t ws_size,
                              hipStream_t stream) {
    (void)in_sizes; (void)n_in; (void)out_size; (void)ws_size;
    const float* x1   = (const float*)d_in[0];
    const float* x2   = (const float*)d_in[1];
    const float* wq1  = (const float*)d_in[2];
    const float* bq1  = (const float*)d_in[3];
    const float* wk1  = (const float*)d_in[4];
    const float* bk1  = (const float*)d_in[5];
    const float* wv1  = (const float*)d_in[6];
    const float* bv1  = (const float*)d_in[7];
    const float* wq2  = (const float*)d_in[8];
    const float* bq2  = (const float*)d_in[9];
    const float* wk2  = (const float*)d_in[10];
    const float* bk2  = (const float*)d_in[11];
    const float* wv2  = (const float*)d_in[12];
    const float* bv2  = (const float*)d_in[13];
    const float* gma  = (const float*)d_in[14];
    const float* wcat = (const float*)d_in[15];
    const float* bns  = (const float*)d_in[16];
    const float* bnb  = (const float*)d_in[17];
    const float* bnm  = (const float*)d_in[18];
    const float* bnv  = (const float*)d_in[19];

    float* out = (float*)d_out;
    unsigned short* wtc = (unsigned short*)d_ws;     // conv weights bf16
    unsigned short* wvb = wtc + WVB_OFF;             // wv bf16 [2][256][256]

    wprep_proj<<<704, 256, 0, stream>>>(wq1, wk1, wv1, wq2, wk2, wv2, out + WTP_OFF);
    wprep_convw<<<4608, 256, 0, stream>>>(wcat, wtc);
    wprep_wv<<<512, 256, 0, stream>>>(wv1, wv2, wvb);
    proj_kernel<<<dim3(64, 2, 4), 256, 0, stream>>>(x1, x2, bq1, bk1, bq2, bk2, out);
    attn_kernel<<<256, 512, 0, stream>>>(x1, x2, wvb, bv1, bv2, gma, out);
    conv_kernel<<<1024, 256, 0, stream>>>(wtc, bns, bnb, bnm, bnv, out);
}

// Round 10
// 402.705 us; speedup vs baseline: 1.0300x; 1.0300x over previous
//
#include <hip/hip_runtime.h>
#include <hip/hip_bf16.h>

#define HW 4096

// ---------------- d_out layout ----------------
// bf16 elements:
//   [0         .. 1,048,576)  q_t [4][4096 n][64 c]   (c: 0..31 br1-q, 32..63 br2-q)
//   [1,048,576 .. 3,145,728)  k_t [2][4][4096 m][64 c]
// fp32 elements:
//   [1,572,864 .. 1,753,088)  wtp [2][256][352] transposed proj weights
//   [4,194,304 .. 8,388,608)  out1   [8,388,608 .. 12,582,912) out2
// d_ws: wt_conv bf16 [32][9][256][16] = 2,359,296 B @ 0
//       wv_bf  bf16 [2][256 o][256 c] =   262,144 B @ 2,359,296
//       xbf    bf16 [2][4][256][4096] = 16,777,216 B @ 2,621,440  (only if ws_size allows)
#define KT_OFF   1048576        // bf16 elements
#define WTP_OFF  1572864        // float elements
#define O1_OFF   4194304        // float elements
#define WVB_OFF  1179648        // bf16 elements into d_ws
#define XBF_OFF  1310720        // shorts into d_ws (byte 2,621,440)
#define WS_NEED  19398656ull    // bytes of d_ws required for the bf16-X path

typedef short v8s  __attribute__((ext_vector_type(8)));
typedef float v16f __attribute__((ext_vector_type(16)));

#define LSTR 72                 // attention LDS row stride (bf16)
#define ZSTR 264                // zt row stride (shorts): cf-free
#define CPAD 20                 // conv LDS ci-stride (bf16)
#define PL_ROWS 128             // plds rows (BN)
#define PL_SZ  (2 * PL_ROWS * LSTR)   // shorts, both plds buffers
#define XP_SZ  (2 * 256 * LSTR)       // shorts, both xpriv buffers
#define XLHALF (4 * 66 * CPAD)        // shorts, one conv xl buffer

__device__ __forceinline__ unsigned short f2b(float f) {   // fp32 -> bf16 RNE
    unsigned u = __float_as_uint(f);
    return (unsigned short)((u + 0x7fffu + ((u >> 16) & 1u)) >> 16);
}
__device__ __forceinline__ unsigned cvt_pk_bf16(float lo, float hi) {  // HW RNE pack via intrinsic
    float2 f2; f2.x = lo; f2.y = hi;
    __hip_bfloat162 h = __float22bfloat162_rn(f2);
    unsigned r;
    __builtin_memcpy(&r, &h, 4);
    return r;
}
__device__ __forceinline__ v8s load8(const unsigned short* p) {  // 8 bf16 via two b64
    union { uint2 u[2]; v8s v; } t;
    t.u[0] = *(const uint2*)p;
    t.u[1] = *(const uint2*)(p + 4);
    return t.v;
}

// ---------------- weight prep: proj weights -> [sel][c][co(352)] fp32 ----------------
__global__ __launch_bounds__(256) void wprep_proj(
    const float* __restrict__ wq1, const float* __restrict__ wk1, const float* __restrict__ wv1,
    const float* __restrict__ wq2, const float* __restrict__ wk2, const float* __restrict__ wv2,
    float* __restrict__ wtp) {
    int idx = blockIdx.x * 256 + threadIdx.x;        // 2*256*352 = 180,224 total
    if (idx >= 2 * 256 * 352) return;
    int sel = idx / 90112;
    int r   = idx - sel * 90112;
    int c   = r / 352;
    int co  = r - c * 352;
    const float* w; int row;
    if (co < 32)      { w = sel ? wq2 : wq1; row = co; }
    else if (co < 96) { w = sel ? wk2 : wk1; row = co - 32; }
    else              { w = sel ? wv2 : wv1; row = co - 96; }
    wtp[idx] = w[row * 256 + c];
}

// ---------------- weight prep: conv w -> bf16 [chunk][tap][o][ci16] ----------------
__global__ __launch_bounds__(256) void wprep_convw(const float* __restrict__ wcat,
                                                   unsigned short* __restrict__ wt) {
    int i = blockIdx.x * 256 + threadIdx.x;          // 1,179,648 total
    if (i >= 32 * 9 * 256 * 16) return;
    const int ci_l = i & 15;
    const int o    = (i >> 4) & 255;
    const int t2   = i >> 12;
    const int tap  = t2 % 9;
    const int chunk = t2 / 9;
    wt[i] = f2b(wcat[((size_t)o * 512 + chunk * 16 + ci_l) * 9 + tap]);
}

// ---------------- weight prep: wv -> bf16 [2][o][c] ----------------
__global__ __launch_bounds__(256) void wprep_wv(const float* __restrict__ wv1,
                                                const float* __restrict__ wv2,
                                                unsigned short* __restrict__ out) {
    int i = blockIdx.x * 256 + threadIdx.x;          // 131,072 total
    if (i >= 131072) return;
    const float* src = (i < 65536) ? wv1 : wv2;
    out[i] = f2b(src[i & 65535]);
}

// ---------------- x prep: in1|in2 -> bf16 [br][b][c][m] ----------------
__global__ __launch_bounds__(256) void wprep_xbf(const float* __restrict__ x1,
                                                 const float* __restrict__ x2,
                                                 unsigned short* __restrict__ xbf) {
    const size_t e = ((size_t)blockIdx.x * 256 + threadIdx.x) * 8;   // 8,388,608 shorts total
    if (e >= 8388608) return;
    const float* src = (e < 4194304) ? (x1 + e) : (x2 + (e - 4194304));
    const float4 a = *(const float4*)src;
    const float4 c = *(const float4*)(src + 4);
    uint4 o;
    o.x = cvt_pk_bf16(a.x, a.y); o.y = cvt_pk_bf16(a.z, a.w);
    o.z = cvt_pk_bf16(c.x, c.y); o.w = cvt_pk_bf16(c.z, c.w);
    *(uint4*)&xbf[e] = o;
}

// ---------------- projections: q|k = W x + b -> bf16 transposed q_t/k_t ----------------
__global__ __launch_bounds__(256) void proj_kernel(
    const float* __restrict__ x1, const float* __restrict__ x2,
    const float* __restrict__ bq1, const float* __restrict__ bk1,
    const float* __restrict__ bq2, const float* __restrict__ bk2,
    float* __restrict__ dout) {
    __shared__ __align__(16) float xls[256][64];     // 64 KB
    const int tile = blockIdx.x, sel = blockIdx.y, b = blockIdx.z;
    const int n0 = tile * 64;
    const float* xb = (sel ? x2 : x1) + (size_t)b * 256 * HW;

    for (int i = threadIdx.x; i < 4096; i += 256) {
        const int row = i >> 4, c4 = (i & 15) * 4;
        *(float4*)&xls[row][c4] = *(const float4*)(xb + (size_t)row * HW + n0 + c4);
    }
    __syncthreads();

    const int n   = threadIdx.x & 63;
    const int cog = __builtin_amdgcn_readfirstlane(threadIdx.x >> 6);   // 0..3, wave-uniform
    const float* bq = sel ? bq2 : bq1;
    const float* bk = sel ? bk2 : bk1;
    const float* wc = dout + WTP_OFF + (size_t)sel * 90112;   // [c][352]
    unsigned short* qtg = (unsigned short*)dout + (size_t)b * HW * 64;
    unsigned short* ktg = (unsigned short*)dout + KT_OFF + (size_t)(sel * 4 + b) * HW * 64;

    for (int blk = 0; blk < 3; ++blk) {              // 4 groups * 24 co = 96
        const int co0 = cog * 24 + blk * 8;          // never straddles the q/k split at 32
        float acc[8];
        const float* brow; int r0; bool isq;
        if (co0 < 32) { r0 = co0;      brow = bq; isq = true;  }
        else          { r0 = co0 - 32; brow = bk; isq = false; }
        #pragma unroll
        for (int k = 0; k < 8; ++k) acc[k] = brow[r0 + k];
        #pragma unroll 4
        for (int c = 0; c < 256; ++c) {
            const float xv = xls[c][n];
            const float4 w0 = *(const float4*)(wc + (size_t)c * 352 + co0);
            const float4 w1 = *(const float4*)(wc + (size_t)c * 352 + co0 + 4);
            acc[0] += xv * w0.x; acc[1] += xv * w0.y; acc[2] += xv * w0.z; acc[3] += xv * w0.w;
            acc[4] += xv * w1.x; acc[5] += xv * w1.y; acc[6] += xv * w1.z; acc[7] += xv * w1.w;
        }
        unsigned pk2[4];
        #pragma unroll
        for (int k = 0; k < 4; ++k) pk2[k] = cvt_pk_bf16(acc[2 * k], acc[2 * k + 1]);
        unsigned short* dst = isq ? (qtg + (size_t)(n0 + n) * 64 + sel * 32 + r0)
                                  : (ktg + (size_t)(n0 + n) * 64 + r0);
        *(uint4*)dst = *(const uint4*)pk2;           // 16B store
    }
}

// ---------------- MFMA attention + fused mix ----------------
// BN=128, 8 waves, 256 blocks = 1 block/CU, XCD swizzle: g=bid&7 <-> (br,b).
// USEBF=1: X read as pre-converted bf16 (no cvt in loop, half the L2 bytes).
template <int USEBF>
__global__ __launch_bounds__(512, 2) void attn_kernel(
    const float* __restrict__ in1, const float* __restrict__ in2,
    const unsigned short* __restrict__ xbf,          // bf16 [2][4][256][4096] (if USEBF)
    const unsigned short* __restrict__ wvbf,         // [2][256 o][256 c] bf16
    const float* __restrict__ bv1, const float* __restrict__ bv2,
    const float* __restrict__ gamma_p,
    float* __restrict__ dout) {
    __shared__ __align__(16) unsigned short smem[PL_SZ + XP_SZ];   // 110,592 B
    __shared__ float rsums[128][2];
    __shared__ float lfin[128];

    const int bid = blockIdx.x;          // 0..255
    const int g   = bid & 7;             // XCD group == (br,b)
    const int qt  = bid >> 3;            // 0..31
    const int br  = g >> 2, b = g & 3;
    const int t = threadIdx.x;
    const int w = t >> 6, lane = t & 63, h = lane >> 5, l32 = lane & 31;

    const unsigned short* qtg = (const unsigned short*)dout + (size_t)b * HW * 64;
    const unsigned short* ktg = (const unsigned short*)dout + KT_OFF + (size_t)(br * 4 + b) * HW * 64;
    const float* xg = (br ? in2 : in1) + (size_t)b * 256 * HW;
    float* zo = dout + O1_OFF + (size_t)br * 4194304 + (size_t)b * 256 * HW;

    // wave roles
    const int msub = (w & 1) * 32;       // S^T m-subtile
    const int nsub = (w >> 1) * 32;      // S^T n-subtile (0..96)
    const int cs   = w & 3;              // zacc c-slice / phase-2 o-slice
    const int nh   = w >> 2;             // zacc / phase-2 n-half (0..1)
    const int koff = h * 8;

    unsigned short* plds = smem;                 // [2][128][LSTR]
    unsigned short* xp   = smem + PL_SZ;         // [2][256][LSTR]

    // persistent Q fragments
    v8s aq[4];
    #pragma unroll
    for (int ks = 0; ks < 4; ++ks)
        aq[ks] = *(const v8s*)(qtg + (size_t)(qt * 128 + nsub + l32) * 64 + ks * 16 + koff);

    // K fragment lane base
    const unsigned short* kpt = ktg + (size_t)(msub + l32) * 64 + koff;
    v8s kf[4];
    #pragma unroll
    for (int ks = 0; ks < 4; ++ks)
        kf[ks] = *(const v8s*)(kpt + ks * 16);

    // x staging: 512 threads stage X[256 c][64 m] per iter.
    const int m4 = (t & 15) * 4, r0i = t >> 4;     // r0i 0..31
    const float* xgp = xg + (size_t)r0i * HW + m4;                       // f32 path
    const unsigned short* xbp = xbf + (size_t)br * 4194304
                              + (size_t)b * 256 * HW + (size_t)r0i * HW + m4;  // bf16 path

    uint2 xpk[8];                // packed bf16 x-tile (pending LDS store)
    if constexpr (USEBF) {
        #pragma unroll
        for (int j = 0; j < 8; ++j) xpk[j] = *(const uint2*)(xbp + (size_t)j * 32 * HW);
    } else {
        float4 xr0[8];
        #pragma unroll
        for (int j = 0; j < 8; ++j) xr0[j] = *(const float4*)(xgp + (size_t)j * 32 * HW);
        #pragma unroll
        for (int j = 0; j < 8; ++j) {
            xpk[j].x = cvt_pk_bf16(xr0[j].x, xr0[j].y);
            xpk[j].y = cvt_pk_bf16(xr0[j].z, xr0[j].w);
        }
    }

    v16f a00, a01, a10, a11;
    #pragma unroll
    for (int i = 0; i < 16; ++i) { a00[i] = 0.f; a01[i] = 0.f; a10[i] = 0.f; a11[i] = 0.f; }
    float racc = 0.f;

    #pragma unroll 1
    for (int mt = 0; mt < 64; ++mt) {
        const int cur = mt & 1;
        // ---- S^T = K Q^T, pure-register MFMA ----
        v16f s;
        #pragma unroll
        for (int i = 0; i < 16; ++i) s[i] = 0.f;
        #pragma unroll
        for (int ks = 0; ks < 4; ++ks)
            s = __builtin_amdgcn_mfma_f32_32x32x16_bf16(kf[ks], aq[ks], s, 0, 0, 0);
        const int mg = (mt < 63) ? (mt + 1) * 64 : 0;          // next tile (wraps harmlessly)
        // prefetch next K fragments
        #pragma unroll
        for (int ks = 0; ks < 4; ++ks)
            kf[ks] = *(const v8s*)(kpt + (size_t)mg * 64 + ks * 16);
        // f32 path: issue next-tile loads now (converted after zacc)
        float4 xr[8];
        if constexpr (!USEBF) {
            #pragma unroll
            for (int j = 0; j < 8; ++j)
                xr[j] = *(const float4*)(xgp + (size_t)j * 32 * HW + mg);
        }
        // ---- P = exp(S^T): scalar row sum, packed m-pairs ----
        unsigned short* prow = plds + (size_t)(cur * PL_ROWS + nsub + l32) * LSTR + msub;
        #pragma unroll
        for (int rp = 0; rp < 8; ++rp) {
            const float e0 = __expf(s[2 * rp]);
            const float e1 = __expf(s[2 * rp + 1]);
            racc += e0 + e1;
            const int m0 = ((2 * rp) & 3) + 8 * (rp >> 1) + 4 * h;   // even
            *(unsigned*)&prow[m0] = cvt_pk_bf16(e0, e1);
        }
        // ---- write current X tile to LDS[cur] ----
        {
            unsigned short* xw = xp + (size_t)(cur * 256 + r0i) * LSTR + m4;
            #pragma unroll
            for (int j = 0; j < 8; ++j)
                *(uint2*)(xw + (size_t)j * 32 * LSTR) = xpk[j];
        }
        // bf16 path: load next tile directly into xpk (flies across barrier + zacc)
        if constexpr (USEBF) {
            #pragma unroll
            for (int j = 0; j < 8; ++j)
                xpk[j] = *(const uint2*)(xbp + (size_t)j * 32 * HW + mg);
        }
        __syncthreads();         // ONE barrier: P/X visible; prior-buffer reads drained
        // ---- zacc: a[c-slice][n-half] += X P^T ----
        {
            const unsigned short* xb0 = xp + (size_t)(cur * 256 + cs * 64 + l32) * LSTR;
            const unsigned short* xb1 = xb0 + (size_t)32 * LSTR;
            const unsigned short* pb0 = plds + (size_t)(cur * PL_ROWS + nh * 64 + l32) * LSTR;
            const unsigned short* pb1 = pb0 + (size_t)32 * LSTR;
            #pragma unroll
            for (int ks = 0; ks < 4; ++ks) {
                const int mo = ks * 16 + koff;
                const v8s xa0 = *(const v8s*)(xb0 + mo);
                const v8s xa1 = *(const v8s*)(xb1 + mo);
                const v8s pf0 = *(const v8s*)(pb0 + mo);
                const v8s pf1 = *(const v8s*)(pb1 + mo);
                a00 = __builtin_amdgcn_mfma_f32_32x32x16_bf16(xa0, pf0, a00, 0, 0, 0);
                a01 = __builtin_amdgcn_mfma_f32_32x32x16_bf16(xa0, pf1, a01, 0, 0, 0);
                a10 = __builtin_amdgcn_mfma_f32_32x32x16_bf16(xa1, pf0, a10, 0, 0, 0);
                a11 = __builtin_amdgcn_mfma_f32_32x32x16_bf16(xa1, pf1, a11, 0, 0, 0);
            }
        }
        // f32 path: convert next tile after zacc
        if constexpr (!USEBF) {
            #pragma unroll
            for (int j = 0; j < 8; ++j) {
                xpk[j].x = cvt_pk_bf16(xr[j].x, xr[j].y);
                xpk[j].y = cvt_pk_bf16(xr[j].z, xr[j].w);
            }
        }
    }
    // ---- softmax denominators ----
    __syncthreads();
    {
        const float rtot = racc + __shfl_xor(racc, 32);
        if (lane < 32) rsums[nsub + l32][w & 1] = rtot;
    }
    __syncthreads();
    if (t < 128) lfin[t] = 1.0f / (rsums[t][0] + rsums[t][1]);
    __syncthreads();
    const float dn0 = lfin[nh * 64 + l32];
    const float dn1 = lfin[nh * 64 + 32 + l32];
    // ---- normalized z -> zt[n][c] bf16 (overlays smem; cf-free stride) ----
    unsigned short (*zt)[ZSTR] = (unsigned short (*)[ZSTR])smem;   // 128 x 264 shorts
    #pragma unroll
    for (int rp = 0; rp < 8; ++rp) {
        const int r = rp * 2;
        const int c = cs * 64 + (r & 3) + 8 * (r >> 2) + 4 * h;    // even; c(r+1)=c+1
        const int n0r = nh * 64 + l32, n1r = nh * 64 + 32 + l32;
        *(unsigned*)&zt[n0r][c]      = cvt_pk_bf16(a00[r] * dn0, a00[r + 1] * dn0);
        *(unsigned*)&zt[n1r][c]      = cvt_pk_bf16(a01[r] * dn1, a01[r + 1] * dn1);
        *(unsigned*)&zt[n0r][c + 32] = cvt_pk_bf16(a10[r] * dn0, a10[r + 1] * dn0);
        *(unsigned*)&zt[n1r][c + 32] = cvt_pk_bf16(a11[r] * dn1, a11[r + 1] * dn1);
    }
    __syncthreads();
    // ---- phase 2: out[o][n] = gamma * (Wv z + bv) + x ----
    const unsigned short* wvb = wvbf + (size_t)br * 65536;   // [o][c] bf16
    const float* bvp = br ? bv2 : bv1;
    const float gamma = gamma_p[0];
    const int ob = cs * 64;
    const int ncol = qt * 128 + nh * 64;
    v16f m00, m01, m10, m11;
    #pragma unroll
    for (int i = 0; i < 16; ++i) { m00[i] = 0.f; m01[i] = 0.f; m10[i] = 0.f; m11[i] = 0.f; }
    #pragma unroll
    for (int ks = 0; ks < 16; ++ks) {
        const int k = ks * 16 + koff;
        const v8s aA = *(const v8s*)(wvb + (size_t)(ob + l32) * 256 + k);
        const v8s aB = *(const v8s*)(wvb + (size_t)(ob + 32 + l32) * 256 + k);
        const v8s b0v = *(const v8s*)&zt[nh * 64 + l32][k];
        const v8s b1v = *(const v8s*)&zt[nh * 64 + 32 + l32][k];
        m00 = __builtin_amdgcn_mfma_f32_32x32x16_bf16(aA, b0v, m00, 0, 0, 0);
        m01 = __builtin_amdgcn_mfma_f32_32x32x16_bf16(aA, b1v, m01, 0, 0, 0);
        m10 = __builtin_amdgcn_mfma_f32_32x32x16_bf16(aB, b0v, m10, 0, 0, 0);
        m11 = __builtin_amdgcn_mfma_f32_32x32x16_bf16(aB, b1v, m11, 0, 0, 0);
    }
    #pragma unroll
    for (int r = 0; r < 16; ++r) {
        const int o = ob + (r & 3) + 8 * (r >> 2) + 4 * h;
        const float bvA = bvp[o], bvB = bvp[o + 32];
        const size_t base0 = (size_t)o * HW + ncol;
        const size_t base1 = (size_t)(o + 32) * HW + ncol;
        zo[base0 + l32]      = gamma * (m00[r] + bvA) + xg[base0 + l32];
        zo[base0 + 32 + l32] = gamma * (m01[r] + bvA) + xg[base0 + 32 + l32];
        zo[base1 + l32]      = gamma * (m10[r] + bvB) + xg[base1 + l32];
        zo[base1 + 32 + l32] = gamma * (m11[r] + bvB) + xg[base1 + 32 + l32];
    }
}

// ---------------- MFMA 3x3 conv (512->256) + BN + ReLU ----------------
// v3 (best measured): double-buffered pipeline + XCD swizzle (4 ot-blocks per
// (pt,b) slice co-locate; wt L2-resident). One barrier per chunk.
__global__ __launch_bounds__(256) void conv_kernel(
    const unsigned short* __restrict__ wt,
    const float* __restrict__ bn_scale, const float* __restrict__ bn_bias,
    const float* __restrict__ bn_mean,  const float* __restrict__ bn_var,
    float* __restrict__ dout) {
    __shared__ __align__(16) unsigned short xl[2][4][66][CPAD];   // 21,120 B
    __shared__ __align__(16) unsigned short wl[2][9][64][CPAD];   // 46,080 B

    const int bid = blockIdx.x;                      // 0..511
    const int xcd = bid & 7, j = bid >> 3;           // j 0..63
    const int G   = xcd * 16 + (j >> 2);             // 0..127 = (pt,b) group
    const int ot  = j & 3;
    const int pt  = G & 31;
    const int b   = G >> 5;
    const int h0 = pt * 2;
    const int t  = threadIdx.x;
    const int w  = t >> 6, lane = t & 63, h = lane >> 5, l32 = lane & 31;
    const int osub = (w & 1) * 32;
    const int ps0  = (w >> 1) * 64;

    int ldsoff[9], srcoff[9]; bool valid[9], inb[9];
    #pragma unroll
    for (int k = 0; k < 9; ++k) {
        const int i = t + k * 256;
        valid[k] = i < 2112;
        const int col = i % 66, rem = i / 66;
        const int row = rem & 3, cp = rem >> 2;
        const int hh = h0 + row - 1, ww = col - 1;
        inb[k] = (hh >= 0 && hh < 64 && ww >= 0 && ww < 64);
        srcoff[k] = 2 * cp * HW + (inb[k] ? hh * 64 + ww : 0);
        ldsoff[k] = (row * 66 + col) * CPAD + 2 * cp;
    }
    unsigned short* xlf = &xl[0][0][0][0];

    float inv[16], add[16];
    #pragma unroll
    for (int r = 0; r < 16; ++r) {
        const int o_g = ot * 64 + osub + (r & 3) + 8 * (r >> 2) + 4 * h;
        const float iv = bn_scale[o_g] * __frsqrt_rn(bn_var[o_g] + 1e-5f);
        inv[r] = iv;
        add[r] = bn_bias[o_g] - bn_mean[o_g] * iv;
    }

    v16f acc0, acc1;
    #pragma unroll
    for (int i = 0; i < 16; ++i) { acc0[i] = 0.f; acc1[i] = 0.f; }

    const float* bsrc = dout + O1_OFF + (size_t)b * 1048576;
    const unsigned short* wbase = wt + (size_t)(ot * 64) * 16;

    // ---- prologue: load chunk 0 into registers ----
    float xv0[9], xv1[9];
    uint2 wr[9];
    {
        const float* src = bsrc;                     // chunk 0: out1, ci 0..15
        #pragma unroll
        for (int k = 0; k < 9; ++k) {
            xv0[k] = 0.f; xv1[k] = 0.f;
            if (valid[k] && inb[k]) {
                const float* p = src + srcoff[k];
                xv0[k] = p[0]; xv1[k] = p[HW];
            }
        }
        #pragma unroll
        for (int u9 = 0; u9 < 9; ++u9) {
            const int u = t + u9 * 256;
            const int tap = u >> 8, rem2 = u & 255;
            const int o = rem2 >> 2, q = rem2 & 3;
            wr[u9] = *(const uint2*)(wbase + ((size_t)tap * 256 + o) * 16 + q * 4);
        }
    }

    #pragma unroll 1
    for (int chunk = 0; chunk < 32; ++chunk) {
        const int cur = chunk & 1;
        // ---- write staged registers to LDS[cur] ----
        #pragma unroll
        for (int k = 0; k < 9; ++k)
            if (valid[k])
                *(unsigned*)&xlf[cur * XLHALF + ldsoff[k]] = cvt_pk_bf16(xv0[k], xv1[k]);
        #pragma unroll
        for (int u9 = 0; u9 < 9; ++u9) {
            const int u = t + u9 * 256;
            const int tap = u >> 8, rem2 = u & 255;
            const int o = rem2 >> 2, q = rem2 & 3;
            *(uint2*)&wl[cur][tap][o][q * 4] = wr[u9];
        }
        // ---- prefetch chunk+1 into registers ----
        if (chunk < 31) {
            const int cn = chunk + 1;
            const float* src = bsrc + (size_t)(cn < 16 ? 0 : 1) * 4194304
                             + (size_t)((cn & 15) * 16) * HW;
            #pragma unroll
            for (int k = 0; k < 9; ++k) {
                xv0[k] = 0.f; xv1[k] = 0.f;
                if (valid[k] && inb[k]) {
                    const float* p = src + srcoff[k];
                    xv0[k] = p[0]; xv1[k] = p[HW];
                }
            }
            const unsigned short* wsl = wbase + (size_t)cn * 36864;
            #pragma unroll
            for (int u9 = 0; u9 < 9; ++u9) {
                const int u = t + u9 * 256;
                const int tap = u >> 8, rem2 = u & 255;
                const int o = rem2 >> 2, q = rem2 & 3;
                wr[u9] = *(const uint2*)(wsl + ((size_t)tap * 256 + o) * 16 + q * 4);
            }
        }
        __syncthreads();         // LDS[cur] visible; chunk-2 reads of LDS[cur] drained
        // ---- MFMA on LDS[cur] ----
        #pragma unroll
        for (int dy = 0; dy < 3; ++dy) {
            #pragma unroll
            for (int dx = 0; dx < 3; ++dx) {
                const v8s af = load8(&wl[cur][dy * 3 + dx][osub + l32][h * 8]);
                const int n0 = ps0 + l32, n1 = ps0 + 32 + l32;
                const v8s b0 = load8(&xl[cur][(n0 >> 6) + dy][(n0 & 63) + dx][h * 8]);
                const v8s b1 = load8(&xl[cur][(n1 >> 6) + dy][(n1 & 63) + dx][h * 8]);
                acc0 = __builtin_amdgcn_mfma_f32_32x32x16_bf16(af, b0, acc0, 0, 0, 0);
                acc1 = __builtin_amdgcn_mfma_f32_32x32x16_bf16(af, b1, acc1, 0, 0, 0);
            }
        }
    }
    const int px0 = ps0 + l32, px1 = ps0 + 32 + l32;
    const size_t gpx0 = (size_t)(h0 + (px0 >> 6)) * 64 + (px0 & 63);
    const size_t gpx1 = (size_t)(h0 + (px1 >> 6)) * 64 + (px1 & 63);
    #pragma unroll
    for (int r = 0; r < 16; ++r) {
        const int o_g = ot * 64 + osub + (r & 3) + 8 * (r >> 2) + 4 * h;
        const size_t obase = ((size_t)b * 256 + o_g) * HW;
        float v0 = acc0[r] * inv[r] + add[r];
        float v1 = acc1[r] * inv[r] + add[r];
        v0 = v0 > 0.f ? v0 : 0.f;
        v1 = v1 > 0.f ? v1 : 0.f;
        dout[obase + gpx0] = v0;
        dout[obase + gpx1] = v1;
    }
}

extern "C" void kernel_launch(void* const* d_in, const int* in_sizes, int n_in,
                              void* d_out, int out_size, void* d_ws, size_t ws_size,
                              hipStream_t stream) {
    (void)in_sizes; (void)n_in; (void)out_size;
    const float* x1   = (const float*)d_in[0];
    const float* x2   = (const float*)d_in[1];
    const float* wq1  = (const float*)d_in[2];
    const float* bq1  = (const float*)d_in[3];
    const float* wk1  = (const float*)d_in[4];
    const float* bk1  = (const float*)d_in[5];
    const float* wv1  = (const float*)d_in[6];
    const float* bv1  = (const float*)d_in[7];
    const float* wq2  = (const float*)d_in[8];
    const float* bq2  = (const float*)d_in[9];
    const float* wk2  = (const float*)d_in[10];
    const float* bk2  = (const float*)d_in[11];
    const float* wv2  = (const float*)d_in[12];
    const float* bv2  = (const float*)d_in[13];
    const float* gma  = (const float*)d_in[14];
    const float* wcat = (const float*)d_in[15];
    const float* bns  = (const float*)d_in[16];
    const float* bnb  = (const float*)d_in[17];
    const float* bnm  = (const float*)d_in[18];
    const float* bnv  = (const float*)d_in[19];

    float* out = (float*)d_out;
    unsigned short* wtc = (unsigned short*)d_ws;     // conv weights bf16
    unsigned short* wvb = wtc + WVB_OFF;             // wv bf16 [2][256][256]
    unsigned short* xbf = wtc + XBF_OFF;             // bf16 X (if workspace allows)
    const bool use_bf = ws_size >= WS_NEED;

    wprep_proj<<<704, 256, 0, stream>>>(wq1, wk1, wv1, wq2, wk2, wv2, out + WTP_OFF);
    wprep_convw<<<4608, 256, 0, stream>>>(wcat, wtc);
    wprep_wv<<<512, 256, 0, stream>>>(wv1, wv2, wvb);
    if (use_bf) wprep_xbf<<<4096, 256, 0, stream>>>(x1, x2, xbf);
    proj_kernel<<<dim3(64, 2, 4), 256, 0, stream>>>(x1, x2, bq1, bk1, bq2, bk2, out);
    if (use_bf)
        attn_kernel<1><<<256, 512, 0, stream>>>(x1, x2, xbf, wvb, bv1, bv2, gma, out);
    else
        attn_kernel<0><<<256, 512, 0, stream>>>(x1, x2, xbf, wvb, bv1, bv2, gma, out);
    conv_kernel<<<512, 256, 0, stream>>>(wtc, bns, bnb, bnm, bnv, out);
}